// Round 18
// baseline (460.755 us; speedup 1.0000x reference)
//
#include <hip/hip_runtime.h>
#include <hip/hip_bf16.h>

#define NN 50000
#define EE 800000
#define BB 64
#define MAXDEG 64

typedef float fx2 __attribute__((ext_vector_type(2)));
typedef short short8 __attribute__((ext_vector_type(8)));
typedef float floatx4 __attribute__((ext_vector_type(4)));

__device__ __forceinline__ short f2bs(float f) {
  __hip_bfloat16 h = __float2bfloat16(f);
  short s;
  __builtin_memcpy(&s, &h, 2);
  return s;
}
__device__ __forceinline__ float blo(unsigned u) {
  union { unsigned i; float f; } c;
  c.i = u << 16;
  return c.f;
}
__device__ __forceinline__ float bhi(unsigned u) {
  union { unsigned i; float f; } c;
  c.i = u & 0xffff0000u;
  return c.f;
}

// ---------------- qkvs body (MFMA GEMM, one output matrix m) --------------
// Used by fused0 (layer 0, FIN=16). KV fp8 8B-interleaved, Q bf16.
template <int FIN, int HC, bool EMB>
__device__ __forceinline__ void qkvs_body(
    short* __restrict__ wt, const int bx, const int m,
    const float* __restrict__ x, const int* __restrict__ node_idx,
    const float* __restrict__ emb, const float* __restrict__ Wq,
    const float* __restrict__ Wk, const float* __restrict__ Wv,
    const float* __restrict__ Ws, const float* __restrict__ bq,
    const float* __restrict__ bk, const float* __restrict__ bv,
    const float* __restrict__ bs, unsigned short* __restrict__ q,
    unsigned char* __restrict__ kv, float* __restrict__ skip) {
  constexpr int KT = (FIN + 31) / 32;
  constexpr int NT = HC / 16;
  constexpr int PSTR = KT * 32 + 8;
  const float* __restrict__ Wm = (m == 0) ? Wq : (m == 1) ? Wk : (m == 2) ? Wv : Ws;
  const float* __restrict__ bm = (m == 0) ? bq : (m == 1) ? bk : (m == 2) ? bv : bs;
  for (int i = threadIdx.x; i < HC * PSTR / 2; i += 256) ((int*)wt)[i] = 0;
  __syncthreads();
  for (int i = threadIdx.x; i < FIN * HC; i += 256) {
    const int k = i / HC, c = i - k * HC;
    wt[c * PSTR + k] = f2bs(Wm[i]);
  }
  __syncthreads();

  const int lane = threadIdx.x & 63;
  const int wid = threadIdx.x >> 6;
  const int fr = lane & 15;
  const int kg = lane >> 4;
  const int node0 = bx * 64 + wid * 16;
  int arow = node0 + fr;
  if (arow > NN - 1) arow = NN - 1;
  const float* __restrict__ xr =
      EMB ? emb + (size_t)node_idx[arow] * 16 : x + (size_t)arow * FIN;

  floatx4 acc[NT];
#pragma unroll
  for (int nt = 0; nt < NT; ++nt) {
    const float b = bm[nt * 16 + fr];
#pragma unroll
    for (int r = 0; r < 4; ++r) acc[nt][r] = b;
  }

#pragma unroll
  for (int kt = 0; kt < KT; ++kt) {
    const int kbase = kt * 32 + kg * 8;
    short8 a = {0, 0, 0, 0, 0, 0, 0, 0};
    if (kbase < FIN) {
      const float4 xa = *(const float4*)(xr + kbase);
      const float4 xb = *(const float4*)(xr + kbase + 4);
      a[0] = f2bs(xa.x); a[1] = f2bs(xa.y); a[2] = f2bs(xa.z); a[3] = f2bs(xa.w);
      a[4] = f2bs(xb.x); a[5] = f2bs(xb.y); a[6] = f2bs(xb.z); a[7] = f2bs(xb.w);
    }
#pragma unroll
    for (int nt = 0; nt < NT; ++nt) {
      const short8 bfr =
          *(const short8*)(&wt[(nt * 16 + fr) * PSTR + kt * 32 + kg * 8]);
      acc[nt] =
          __builtin_amdgcn_mfma_f32_16x16x32_bf16(a, bfr, acc[nt], 0, 0, 0);
    }
  }

#pragma unroll
  for (int nt = 0; nt < NT; ++nt) {
    const int ch = nt * 16 + fr;
#pragma unroll
    for (int r = 0; r < 4; ++r) {
      const int node = node0 + kg * 4 + r;
      if (node >= NN) continue;
      const float val = acc[nt][r];
      if (m == 1 || m == 2) {
        const int w = __builtin_amdgcn_cvt_pk_fp8_f32(val, val, 0, false);
        kv[(size_t)node * (2 * HC) + (ch >> 2) * 8 + (ch & 3) +
           (m == 2 ? 4 : 0)] = (unsigned char)(w & 0xff);
      } else if (m == 0) {
        q[(size_t)node * HC + ch] = (unsigned short)f2bs(val);
      } else {
        skip[(size_t)node * HC + ch] = val;
      }
    }
  }
}

// ---------------- K1b: layers 1-2 — all 4 matrices in ONE block -----------
template <int HC>
__global__ __launch_bounds__(256) void k_qkvs4(
    const float* __restrict__ x, const float* __restrict__ Wq,
    const float* __restrict__ Wk, const float* __restrict__ Wv,
    const float* __restrict__ Ws, const float* __restrict__ bq,
    const float* __restrict__ bk, const float* __restrict__ bv,
    const float* __restrict__ bs, unsigned short* __restrict__ q,
    unsigned char* __restrict__ kv, float* __restrict__ skip) {
  constexpr int FIN = 96;
  constexpr int KT = 3;
  constexpr int NT = HC / 16;
  constexpr int PSTR = 96 + 8;
  __shared__ short wt[HC * PSTR];
  const int lane = threadIdx.x & 63;
  const int wid = threadIdx.x >> 6;
  const int fr = lane & 15;
  const int kg = lane >> 4;
  const int node0 = blockIdx.x * 64 + wid * 16;
  int arow = node0 + fr;
  if (arow > NN - 1) arow = NN - 1;
  const float* __restrict__ xr = x + (size_t)arow * FIN;

  short8 afrag[KT];
#pragma unroll
  for (int kt = 0; kt < KT; ++kt) {
    const int kbase = kt * 32 + kg * 8;
    const float4 xa = *(const float4*)(xr + kbase);
    const float4 xb = *(const float4*)(xr + kbase + 4);
    short8 a;
    a[0] = f2bs(xa.x); a[1] = f2bs(xa.y); a[2] = f2bs(xa.z); a[3] = f2bs(xa.w);
    a[4] = f2bs(xb.x); a[5] = f2bs(xb.y); a[6] = f2bs(xb.z); a[7] = f2bs(xb.w);
    afrag[kt] = a;
  }

  const float* W[4] = {Wq, Wk, Wv, Ws};
  const float* bias[4] = {bq, bk, bv, bs};
#pragma unroll
  for (int m = 0; m < 4; ++m) {
    if (m) __syncthreads();
    const float* __restrict__ Wm = W[m];
    for (int i = threadIdx.x; i < FIN * HC; i += 256) {
      const int k = i / HC, c = i - k * HC;
      wt[c * PSTR + k] = f2bs(Wm[i]);
    }
    __syncthreads();

    floatx4 acc[NT];
#pragma unroll
    for (int nt = 0; nt < NT; ++nt) {
      const float b = bias[m][nt * 16 + fr];
#pragma unroll
      for (int r = 0; r < 4; ++r) acc[nt][r] = b;
    }
#pragma unroll
    for (int kt = 0; kt < KT; ++kt) {
#pragma unroll
      for (int nt = 0; nt < NT; ++nt) {
        const short8 bfr =
            *(const short8*)(&wt[(nt * 16 + fr) * PSTR + kt * 32 + kg * 8]);
        acc[nt] = __builtin_amdgcn_mfma_f32_16x16x32_bf16(afrag[kt], bfr,
                                                          acc[nt], 0, 0, 0);
      }
    }
#pragma unroll
    for (int nt = 0; nt < NT; ++nt) {
      const int ch = nt * 16 + fr;
#pragma unroll
      for (int r = 0; r < 4; ++r) {
        const int node = node0 + kg * 4 + r;
        if (node >= NN) continue;
        const float val = acc[nt][r];
        if (m == 1 || m == 2) {
          const int w = __builtin_amdgcn_cvt_pk_fp8_f32(val, val, 0, false);
          kv[(size_t)node * (2 * HC) + (ch >> 2) * 8 + (ch & 3) +
             (m == 2 ? 4 : 0)] = (unsigned char)(w & 0xff);
        } else if (m == 0) {
          q[(size_t)node * HC + ch] = (unsigned short)f2bs(val);
        } else {
          skip[(size_t)node * HC + ch] = val;
        }
      }
    }
  }
}

// ---------------- Fused dispatch: ELL scatter || layer-0 qkvs || GS zero --
#define SBLK ((EE + 255) / 256)          // 3125 scatter blocks
#define QBLK0 (((NN + 63) / 64) * 4)     // 3128 qkvs blocks (782 x 4)

__global__ __launch_bounds__(256) void k_fused0(
    const int* __restrict__ ei, int* __restrict__ cursor,
    unsigned short* __restrict__ ell, const int* __restrict__ node_idx,
    const float* __restrict__ emb, const float* __restrict__ Wq,
    const float* __restrict__ Wk, const float* __restrict__ Wv,
    const float* __restrict__ Ws, const float* __restrict__ bq,
    const float* __restrict__ bk, const float* __restrict__ bv,
    const float* __restrict__ bs, unsigned short* __restrict__ q,
    unsigned char* __restrict__ kv, float* __restrict__ skip,
    float* __restrict__ gsum) {
  constexpr int PSTR0 = 32 + 8;  // FIN=16 -> KT=1
  __shared__ short wt[96 * PSTR0];
  const int bid = blockIdx.x;
  if (bid & 1) {
    const int idx = bid >> 1;
    if (idx < QBLK0)
      qkvs_body<16, 96, true>(wt, idx >> 2, idx & 3, nullptr, node_idx, emb,
                              Wq, Wk, Wv, Ws, bq, bk, bv, bs, q, kv, skip);
  } else {
    const int sbid = bid >> 1;
    if (sbid < SBLK) {
      const int e = sbid * 256 + threadIdx.x;
      if (e < EE) {
        const int d = ei[EE + e];
        const int slot = atomicAdd(&cursor[d], 1);
        if (slot < MAXDEG)
          __builtin_nontemporal_store((unsigned short)ei[e],
                                      &ell[(unsigned)d * MAXDEG + slot]);
      }
    } else if (sbid == SBLK) {
      for (int i = threadIdx.x; i < BB * 64; i += 256) gsum[i] = 0.f;
    }
  }
}

// ---------------- K2: gather aggregation, fp8 KV, 4x unroll ---------------
// POOL=true (last layer): skip X write; atomicAdd node row into gsum.
constexpr float scale_of(int c) {
  return c == 32 ? 0.17677669529663687f
                 : (c == 64 ? 0.125f : 0.10206207261596575f);
}

template <int H, int C, bool POOL>
__global__ __launch_bounds__(256) void k_agg(
    const int* __restrict__ deg_arr, const unsigned short* __restrict__ ell,
    const unsigned short* __restrict__ q, const unsigned char* __restrict__ kv,
    float* __restrict__ xout, const int* __restrict__ batch,
    float* __restrict__ gsum) {
  constexpr int HC = H * C;
  constexpr int ROW = HC / 4;
  constexpr int LG = (ROW > 16) ? 32 : 16;
  constexpr int G = 64 / LG;
  constexpr int RW = (H == 1) ? LG : 8;
  const int n = blockIdx.x * (256 / 64) + (threadIdx.x >> 6);
  if (n >= NN) return;
  const int lane = threadIdx.x & 63;
  const int g = lane / LG;
  const int cl = lane % LG;
  const bool act = cl < ROW;
  fx2 q01 = {0.f, 0.f}, q23 = {0.f, 0.f};
  if (act) {
    const uint2 uq = ((const uint2*)(q + (size_t)n * HC))[cl];
    q01[0] = blo(uq.x); q01[1] = bhi(uq.x);
    q23[0] = blo(uq.y); q23[1] = bhi(uq.y);
  }
  const unsigned coff = 8u * (unsigned)cl;
  fx2 accL = {0.f, 0.f}, accH = {0.f, 0.f};
  float den = 0.f;
  const int deg = min(deg_arr[n], MAXDEG);
  const unsigned short* __restrict__ row = ell + (unsigned)n * MAXDEG;
  int i = g;
  for (; i + 3 * G < deg; i += 4 * G) {
    const unsigned s0 = row[i];
    const unsigned s1 = row[i + G];
    const unsigned s2 = row[i + 2 * G];
    const unsigned s3 = row[i + 3 * G];
    uint2 u0 = {0, 0}, u1 = {0, 0}, u2 = {0, 0}, u3 = {0, 0};
    if (act) {
      u0 = *(const uint2*)(kv + (size_t)(s0 * (2 * HC)) + coff);
      u1 = *(const uint2*)(kv + (size_t)(s1 * (2 * HC)) + coff);
      u2 = *(const uint2*)(kv + (size_t)(s2 * (2 * HC)) + coff);
      u3 = *(const uint2*)(kv + (size_t)(s3 * (2 * HC)) + coff);
    }
    fx2 t0 = q01 * __builtin_amdgcn_cvt_pk_f32_fp8(u0.x, false) +
             q23 * __builtin_amdgcn_cvt_pk_f32_fp8(u0.x, true);
    fx2 t1 = q01 * __builtin_amdgcn_cvt_pk_f32_fp8(u1.x, false) +
             q23 * __builtin_amdgcn_cvt_pk_f32_fp8(u1.x, true);
    fx2 t2 = q01 * __builtin_amdgcn_cvt_pk_f32_fp8(u2.x, false) +
             q23 * __builtin_amdgcn_cvt_pk_f32_fp8(u2.x, true);
    fx2 t3 = q01 * __builtin_amdgcn_cvt_pk_f32_fp8(u3.x, false) +
             q23 * __builtin_amdgcn_cvt_pk_f32_fp8(u3.x, true);
    float d0 = t0[0] + t0[1];
    float d1 = t1[0] + t1[1];
    float d2 = t2[0] + t2[1];
    float d3 = t3[0] + t3[1];
#pragma unroll
    for (int m = 1; m < RW; m <<= 1) {
      d0 += __shfl_xor(d0, m);
      d1 += __shfl_xor(d1, m);
      d2 += __shfl_xor(d2, m);
      d3 += __shfl_xor(d3, m);
    }
    const float e0 = __expf(d0 * scale_of(C));
    const float e1 = __expf(d1 * scale_of(C));
    const float e2 = __expf(d2 * scale_of(C));
    const float e3 = __expf(d3 * scale_of(C));
    den += (e0 + e1) + (e2 + e3);
    const fx2 e0v = {e0, e0}, e1v = {e1, e1}, e2v = {e2, e2}, e3v = {e3, e3};
    accL += e0v * __builtin_amdgcn_cvt_pk_f32_fp8(u0.y, false) +
            e1v * __builtin_amdgcn_cvt_pk_f32_fp8(u1.y, false);
    accL += e2v * __builtin_amdgcn_cvt_pk_f32_fp8(u2.y, false) +
            e3v * __builtin_amdgcn_cvt_pk_f32_fp8(u3.y, false);
    accH += e0v * __builtin_amdgcn_cvt_pk_f32_fp8(u0.y, true) +
            e1v * __builtin_amdgcn_cvt_pk_f32_fp8(u1.y, true);
    accH += e2v * __builtin_amdgcn_cvt_pk_f32_fp8(u2.y, true) +
            e3v * __builtin_amdgcn_cvt_pk_f32_fp8(u3.y, true);
  }
  for (; i < deg; i += G) {
    const unsigned s0 = row[i];
    uint2 u0 = {0, 0};
    if (act) u0 = *(const uint2*)(kv + (size_t)(s0 * (2 * HC)) + coff);
    fx2 t0 = q01 * __builtin_amdgcn_cvt_pk_f32_fp8(u0.x, false) +
             q23 * __builtin_amdgcn_cvt_pk_f32_fp8(u0.x, true);
    float d0 = t0[0] + t0[1];
#pragma unroll
    for (int m = 1; m < RW; m <<= 1) d0 += __shfl_xor(d0, m);
    const float e0 = __expf(d0 * scale_of(C));
    den += e0;
    const fx2 e0v = {e0, e0};
    accL += e0v * __builtin_amdgcn_cvt_pk_f32_fp8(u0.y, false);
    accH += e0v * __builtin_amdgcn_cvt_pk_f32_fp8(u0.y, true);
  }
#pragma unroll
  for (int m = LG; m < 64; m <<= 1) {
    den += __shfl_xor(den, m);
    accL[0] += __shfl_xor(accL[0], m);
    accL[1] += __shfl_xor(accL[1], m);
    accH[0] += __shfl_xor(accH[0], m);
    accH[1] += __shfl_xor(accH[1], m);
  }
  if (lane < ROW) {
    const float inv = 1.f / (den + 1e-16f);
    float4* o = (float4*)(xout + (size_t)n * HC);
    float4 c = o[lane];
    c.x += accL[0] * inv;
    c.y += accL[1] * inv;
    c.z += accH[0] * inv;
    c.w += accH[1] * inv;
    if (!POOL) {
      o[lane] = c;
    } else {
      float* gs = gsum + batch[n] * 64 + lane * 4;
      atomicAdd(gs + 0, c.x);
      atomicAdd(gs + 1, c.y);
      atomicAdd(gs + 2, c.z);
      atomicAdd(gs + 3, c.w);
    }
  }
}

// ---------------- K5: final MLP (divide-by-count folded in) ----------------
__device__ __forceinline__ int lowerb(const int* __restrict__ b, int n,
                                      int key) {
  int lo = 0, hi = n;
  while (lo < hi) {
    int mid = (lo + hi) >> 1;
    if (b[mid] < key) lo = mid + 1;
    else hi = mid;
  }
  return lo;
}

__global__ void k_mlp(const float* __restrict__ gsum,
                      const int* __restrict__ batch,
                      const float* __restrict__ demo,
                      const float* __restrict__ W1,
                      const float* __restrict__ b1,
                      const float* __restrict__ W2,
                      const float* __restrict__ b2, float* __restrict__ out) {
  const int b = threadIdx.x;
  if (b >= BB) return;
  const int lo = lowerb(batch, NN, b);
  const int hi = lowerb(batch, NN, b + 1);
  const float inv = 1.f / (float)max(hi - lo, 1);
  float f[69];
#pragma unroll
  for (int t = 0; t < 64; ++t) f[t] = gsum[b * 64 + t] * inv;
#pragma unroll
  for (int t = 0; t < 5; ++t) f[64 + t] = demo[b * 5 + t];
  float o0 = b2[0], o1 = b2[1];
  for (int jm = 0; jm < 32; ++jm) {
    float h = b1[jm];
#pragma unroll
    for (int t = 0; t < 69; ++t) h += f[t] * W1[t * 32 + jm];
    h = fmaxf(h, 0.f);
    o0 += h * W2[jm * 2 + 0];
    o1 += h * W2[jm * 2 + 1];
  }
  out[b * 2 + 0] = o0;
  out[b * 2 + 1] = o1;
}

extern "C" void kernel_launch(void* const* d_in, const int* in_sizes, int n_in,
                              void* d_out, int out_size, void* d_ws,
                              size_t ws_size, hipStream_t stream) {
  const int* node_idx = (const int*)d_in[0];
  const int* ei = (const int*)d_in[1];
  const int* batch = (const int*)d_in[2];
  const float* demo = (const float*)d_in[3];
  const float* emb = (const float*)d_in[4];
  const float* P[24];
  for (int i = 0; i < 24; ++i) P[i] = (const float*)d_in[5 + i];
  const float* W1 = (const float*)d_in[29];
  const float* b1 = (const float*)d_in[30];
  const float* W2 = (const float*)d_in[31];
  const float* b2 = (const float*)d_in[32];

  const size_t NS = (size_t)NN * 96;
  float* X0 = (float*)d_ws;
  float* X1 = X0 + NS;
  unsigned short* Q = (unsigned short*)(X0 + 2 * NS);  // NN*96 bf16
  unsigned char* KV = (unsigned char*)(X0 + 3 * NS);   // NN*192 bytes
  int* cursor = (int*)(X0 + 3 * NS + NS / 2);          // NN (== degree)
  unsigned short* ell = (unsigned short*)(cursor + NN);  // NN*MAXDEG u16
  float* GS = (float*)(ell + (size_t)NN * MAXDEG);     // 64*64 partial sums

  hipMemsetAsync(cursor, 0, NN * sizeof(int), stream);

  // fused: ELL scatter (even blocks) || layer-0 qkvs (odd blocks) || GS zero
  {
    const float* const* p = &P[0];
    const int nfb = 2 * ((SBLK + 1 > QBLK0) ? (SBLK + 1) : QBLK0);
    k_fused0<<<nfb, 256, 0, stream>>>(ei, cursor, ell, node_idx, emb, p[0],
                                      p[1], p[2], p[3], p[4], p[5], p[6], p[7],
                                      Q, KV, X1, GS);
  }

  const int nwb = (NN * 64 + 255) / 256;  // one wave per node
  k_agg<3, 32, false><<<nwb, 256, 0, stream>>>(cursor, ell, Q, KV, X1,
                                               nullptr, nullptr);

  // layer 1: FIN=96 HC=96 H=1 C=96  (in X1, skip/out X0)
  {
    const float* const* p = &P[8];
    k_qkvs4<96><<<(NN + 63) / 64, 256, 0, stream>>>(
        X1, p[0], p[1], p[2], p[3], p[4], p[5], p[6], p[7], Q, KV, X0);
    k_agg<1, 96, false><<<nwb, 256, 0, stream>>>(cursor, ell, Q, KV, X0,
                                                 nullptr, nullptr);
  }
  // layer 2: FIN=96 HC=64 H=1 C=64  (in X0, skip/out X1; pool fused)
  {
    const float* const* p = &P[16];
    k_qkvs4<64><<<(NN + 63) / 64, 256, 0, stream>>>(
        X0, p[0], p[1], p[2], p[3], p[4], p[5], p[6], p[7], Q, KV, X1);
    k_agg<1, 64, true><<<nwb, 256, 0, stream>>>(cursor, ell, Q, KV, X1, batch,
                                                GS);
  }

  k_mlp<<<1, 64, 0, stream>>>(GS, batch, demo, W1, b1, W2, b2, (float*)d_out);
}

// Round 19
// 256.564 us; speedup vs baseline: 1.7959x; 1.7959x over previous
//
#include <hip/hip_runtime.h>
#include <hip/hip_bf16.h>

#define NN 50000
#define EE 800000
#define BB 64
#define MAXDEG 64

typedef float fx2 __attribute__((ext_vector_type(2)));
typedef short short8 __attribute__((ext_vector_type(8)));
typedef float floatx4 __attribute__((ext_vector_type(4)));

__device__ __forceinline__ short f2bs(float f) {
  __hip_bfloat16 h = __float2bfloat16(f);
  short s;
  __builtin_memcpy(&s, &h, 2);
  return s;
}
__device__ __forceinline__ float blo(unsigned u) {
  union { unsigned i; float f; } c;
  c.i = u << 16;
  return c.f;
}
__device__ __forceinline__ float bhi(unsigned u) {
  union { unsigned i; float f; } c;
  c.i = u & 0xffff0000u;
  return c.f;
}

// ---------------- qkvs body (MFMA GEMM, one output matrix m) --------------
// Used by fused0 (layer 0, FIN=16). KV fp8 8B-interleaved, Q bf16.
template <int FIN, int HC, bool EMB>
__device__ __forceinline__ void qkvs_body(
    short* __restrict__ wt, const int bx, const int m,
    const float* __restrict__ x, const int* __restrict__ node_idx,
    const float* __restrict__ emb, const float* __restrict__ Wq,
    const float* __restrict__ Wk, const float* __restrict__ Wv,
    const float* __restrict__ Ws, const float* __restrict__ bq,
    const float* __restrict__ bk, const float* __restrict__ bv,
    const float* __restrict__ bs, unsigned short* __restrict__ q,
    unsigned char* __restrict__ kv, float* __restrict__ skip) {
  constexpr int KT = (FIN + 31) / 32;
  constexpr int NT = HC / 16;
  constexpr int PSTR = KT * 32 + 8;
  const float* __restrict__ Wm = (m == 0) ? Wq : (m == 1) ? Wk : (m == 2) ? Wv : Ws;
  const float* __restrict__ bm = (m == 0) ? bq : (m == 1) ? bk : (m == 2) ? bv : bs;
  for (int i = threadIdx.x; i < HC * PSTR / 2; i += 256) ((int*)wt)[i] = 0;
  __syncthreads();
  for (int i = threadIdx.x; i < FIN * HC; i += 256) {
    const int k = i / HC, c = i - k * HC;
    wt[c * PSTR + k] = f2bs(Wm[i]);
  }
  __syncthreads();

  const int lane = threadIdx.x & 63;
  const int wid = threadIdx.x >> 6;
  const int fr = lane & 15;
  const int kg = lane >> 4;
  const int node0 = bx * 64 + wid * 16;
  int arow = node0 + fr;
  if (arow > NN - 1) arow = NN - 1;
  const float* __restrict__ xr =
      EMB ? emb + (size_t)node_idx[arow] * 16 : x + (size_t)arow * FIN;

  floatx4 acc[NT];
#pragma unroll
  for (int nt = 0; nt < NT; ++nt) {
    const float b = bm[nt * 16 + fr];
#pragma unroll
    for (int r = 0; r < 4; ++r) acc[nt][r] = b;
  }

#pragma unroll
  for (int kt = 0; kt < KT; ++kt) {
    const int kbase = kt * 32 + kg * 8;
    short8 a = {0, 0, 0, 0, 0, 0, 0, 0};
    if (kbase < FIN) {
      const float4 xa = *(const float4*)(xr + kbase);
      const float4 xb = *(const float4*)(xr + kbase + 4);
      a[0] = f2bs(xa.x); a[1] = f2bs(xa.y); a[2] = f2bs(xa.z); a[3] = f2bs(xa.w);
      a[4] = f2bs(xb.x); a[5] = f2bs(xb.y); a[6] = f2bs(xb.z); a[7] = f2bs(xb.w);
    }
#pragma unroll
    for (int nt = 0; nt < NT; ++nt) {
      const short8 bfr =
          *(const short8*)(&wt[(nt * 16 + fr) * PSTR + kt * 32 + kg * 8]);
      acc[nt] =
          __builtin_amdgcn_mfma_f32_16x16x32_bf16(a, bfr, acc[nt], 0, 0, 0);
    }
  }

#pragma unroll
  for (int nt = 0; nt < NT; ++nt) {
    const int ch = nt * 16 + fr;
#pragma unroll
    for (int r = 0; r < 4; ++r) {
      const int node = node0 + kg * 4 + r;
      if (node >= NN) continue;
      const float val = acc[nt][r];
      if (m == 1 || m == 2) {
        const int w = __builtin_amdgcn_cvt_pk_fp8_f32(val, val, 0, false);
        kv[(size_t)node * (2 * HC) + (ch >> 2) * 8 + (ch & 3) +
           (m == 2 ? 4 : 0)] = (unsigned char)(w & 0xff);
      } else if (m == 0) {
        q[(size_t)node * HC + ch] = (unsigned short)f2bs(val);
      } else {
        skip[(size_t)node * HC + ch] = val;
      }
    }
  }
}

// ---------------- K1b: layers 1-2 — all 4 matrices in ONE block -----------
template <int HC>
__global__ __launch_bounds__(256) void k_qkvs4(
    const float* __restrict__ x, const float* __restrict__ Wq,
    const float* __restrict__ Wk, const float* __restrict__ Wv,
    const float* __restrict__ Ws, const float* __restrict__ bq,
    const float* __restrict__ bk, const float* __restrict__ bv,
    const float* __restrict__ bs, unsigned short* __restrict__ q,
    unsigned char* __restrict__ kv, float* __restrict__ skip) {
  constexpr int FIN = 96;
  constexpr int KT = 3;
  constexpr int NT = HC / 16;
  constexpr int PSTR = 96 + 8;
  __shared__ short wt[HC * PSTR];
  const int lane = threadIdx.x & 63;
  const int wid = threadIdx.x >> 6;
  const int fr = lane & 15;
  const int kg = lane >> 4;
  const int node0 = blockIdx.x * 64 + wid * 16;
  int arow = node0 + fr;
  if (arow > NN - 1) arow = NN - 1;
  const float* __restrict__ xr = x + (size_t)arow * FIN;

  short8 afrag[KT];
#pragma unroll
  for (int kt = 0; kt < KT; ++kt) {
    const int kbase = kt * 32 + kg * 8;
    const float4 xa = *(const float4*)(xr + kbase);
    const float4 xb = *(const float4*)(xr + kbase + 4);
    short8 a;
    a[0] = f2bs(xa.x); a[1] = f2bs(xa.y); a[2] = f2bs(xa.z); a[3] = f2bs(xa.w);
    a[4] = f2bs(xb.x); a[5] = f2bs(xb.y); a[6] = f2bs(xb.z); a[7] = f2bs(xb.w);
    afrag[kt] = a;
  }

  const float* W[4] = {Wq, Wk, Wv, Ws};
  const float* bias[4] = {bq, bk, bv, bs};
#pragma unroll
  for (int m = 0; m < 4; ++m) {
    if (m) __syncthreads();
    const float* __restrict__ Wm = W[m];
    for (int i = threadIdx.x; i < FIN * HC; i += 256) {
      const int k = i / HC, c = i - k * HC;
      wt[c * PSTR + k] = f2bs(Wm[i]);
    }
    __syncthreads();

    floatx4 acc[NT];
#pragma unroll
    for (int nt = 0; nt < NT; ++nt) {
      const float b = bias[m][nt * 16 + fr];
#pragma unroll
      for (int r = 0; r < 4; ++r) acc[nt][r] = b;
    }
#pragma unroll
    for (int kt = 0; kt < KT; ++kt) {
#pragma unroll
      for (int nt = 0; nt < NT; ++nt) {
        const short8 bfr =
            *(const short8*)(&wt[(nt * 16 + fr) * PSTR + kt * 32 + kg * 8]);
        acc[nt] = __builtin_amdgcn_mfma_f32_16x16x32_bf16(afrag[kt], bfr,
                                                          acc[nt], 0, 0, 0);
      }
    }
#pragma unroll
    for (int nt = 0; nt < NT; ++nt) {
      const int ch = nt * 16 + fr;
#pragma unroll
      for (int r = 0; r < 4; ++r) {
        const int node = node0 + kg * 4 + r;
        if (node >= NN) continue;
        const float val = acc[nt][r];
        if (m == 1 || m == 2) {
          const int w = __builtin_amdgcn_cvt_pk_fp8_f32(val, val, 0, false);
          kv[(size_t)node * (2 * HC) + (ch >> 2) * 8 + (ch & 3) +
             (m == 2 ? 4 : 0)] = (unsigned char)(w & 0xff);
        } else if (m == 0) {
          q[(size_t)node * HC + ch] = (unsigned short)f2bs(val);
        } else {
          skip[(size_t)node * HC + ch] = val;
        }
      }
    }
  }
}

// ---------------- Fused dispatch: ELL scatter || layer-0 qkvs || GS zero --
#define SBLK ((EE + 255) / 256)          // 3125 scatter blocks
#define QBLK0 (((NN + 63) / 64) * 4)     // 3128 qkvs blocks (782 x 4)

__global__ __launch_bounds__(256) void k_fused0(
    const int* __restrict__ ei, int* __restrict__ cursor,
    unsigned short* __restrict__ ell, const int* __restrict__ node_idx,
    const float* __restrict__ emb, const float* __restrict__ Wq,
    const float* __restrict__ Wk, const float* __restrict__ Wv,
    const float* __restrict__ Ws, const float* __restrict__ bq,
    const float* __restrict__ bk, const float* __restrict__ bv,
    const float* __restrict__ bs, unsigned short* __restrict__ q,
    unsigned char* __restrict__ kv, float* __restrict__ skip,
    float* __restrict__ gsum) {
  constexpr int PSTR0 = 32 + 8;  // FIN=16 -> KT=1
  __shared__ short wt[96 * PSTR0];
  const int bid = blockIdx.x;
  if (bid & 1) {
    const int idx = bid >> 1;
    if (idx < QBLK0)
      qkvs_body<16, 96, true>(wt, idx >> 2, idx & 3, nullptr, node_idx, emb,
                              Wq, Wk, Wv, Ws, bq, bk, bv, bs, q, kv, skip);
  } else {
    const int sbid = bid >> 1;
    if (sbid < SBLK) {
      const int e = sbid * 256 + threadIdx.x;
      if (e < EE) {
        const int d = ei[EE + e];
        const int slot = atomicAdd(&cursor[d], 1);
        if (slot < MAXDEG)
          __builtin_nontemporal_store((unsigned short)ei[e],
                                      &ell[(unsigned)d * MAXDEG + slot]);
      }
    } else if (sbid == SBLK) {
      for (int i = threadIdx.x; i < BB * 64; i += 256) gsum[i] = 0.f;
    }
  }
}

// ---------------- K2: gather aggregation, fp8 KV, 4x unroll ---------------
constexpr float scale_of(int c) {
  return c == 32 ? 0.17677669529663687f
                 : (c == 64 ? 0.125f : 0.10206207261596575f);
}

template <int H, int C>
__global__ __launch_bounds__(256) void k_agg(
    const int* __restrict__ deg_arr, const unsigned short* __restrict__ ell,
    const unsigned short* __restrict__ q, const unsigned char* __restrict__ kv,
    float* __restrict__ xout) {
  constexpr int HC = H * C;
  constexpr int ROW = HC / 4;
  constexpr int LG = (ROW > 16) ? 32 : 16;
  constexpr int G = 64 / LG;
  constexpr int RW = (H == 1) ? LG : 8;
  const int n = blockIdx.x * (256 / 64) + (threadIdx.x >> 6);
  if (n >= NN) return;
  const int lane = threadIdx.x & 63;
  const int g = lane / LG;
  const int cl = lane % LG;
  const bool act = cl < ROW;
  fx2 q01 = {0.f, 0.f}, q23 = {0.f, 0.f};
  if (act) {
    const uint2 uq = ((const uint2*)(q + (size_t)n * HC))[cl];
    q01[0] = blo(uq.x); q01[1] = bhi(uq.x);
    q23[0] = blo(uq.y); q23[1] = bhi(uq.y);
  }
  const unsigned coff = 8u * (unsigned)cl;
  fx2 accL = {0.f, 0.f}, accH = {0.f, 0.f};
  float den = 0.f;
  const int deg = min(deg_arr[n], MAXDEG);
  const unsigned short* __restrict__ row = ell + (unsigned)n * MAXDEG;
  int i = g;
  for (; i + 3 * G < deg; i += 4 * G) {
    const unsigned s0 = row[i];
    const unsigned s1 = row[i + G];
    const unsigned s2 = row[i + 2 * G];
    const unsigned s3 = row[i + 3 * G];
    uint2 u0 = {0, 0}, u1 = {0, 0}, u2 = {0, 0}, u3 = {0, 0};
    if (act) {
      u0 = *(const uint2*)(kv + (size_t)(s0 * (2 * HC)) + coff);
      u1 = *(const uint2*)(kv + (size_t)(s1 * (2 * HC)) + coff);
      u2 = *(const uint2*)(kv + (size_t)(s2 * (2 * HC)) + coff);
      u3 = *(const uint2*)(kv + (size_t)(s3 * (2 * HC)) + coff);
    }
    fx2 t0 = q01 * __builtin_amdgcn_cvt_pk_f32_fp8(u0.x, false) +
             q23 * __builtin_amdgcn_cvt_pk_f32_fp8(u0.x, true);
    fx2 t1 = q01 * __builtin_amdgcn_cvt_pk_f32_fp8(u1.x, false) +
             q23 * __builtin_amdgcn_cvt_pk_f32_fp8(u1.x, true);
    fx2 t2 = q01 * __builtin_amdgcn_cvt_pk_f32_fp8(u2.x, false) +
             q23 * __builtin_amdgcn_cvt_pk_f32_fp8(u2.x, true);
    fx2 t3 = q01 * __builtin_amdgcn_cvt_pk_f32_fp8(u3.x, false) +
             q23 * __builtin_amdgcn_cvt_pk_f32_fp8(u3.x, true);
    float d0 = t0[0] + t0[1];
    float d1 = t1[0] + t1[1];
    float d2 = t2[0] + t2[1];
    float d3 = t3[0] + t3[1];
#pragma unroll
    for (int m = 1; m < RW; m <<= 1) {
      d0 += __shfl_xor(d0, m);
      d1 += __shfl_xor(d1, m);
      d2 += __shfl_xor(d2, m);
      d3 += __shfl_xor(d3, m);
    }
    const float e0 = __expf(d0 * scale_of(C));
    const float e1 = __expf(d1 * scale_of(C));
    const float e2 = __expf(d2 * scale_of(C));
    const float e3 = __expf(d3 * scale_of(C));
    den += (e0 + e1) + (e2 + e3);
    const fx2 e0v = {e0, e0}, e1v = {e1, e1}, e2v = {e2, e2}, e3v = {e3, e3};
    accL += e0v * __builtin_amdgcn_cvt_pk_f32_fp8(u0.y, false) +
            e1v * __builtin_amdgcn_cvt_pk_f32_fp8(u1.y, false);
    accL += e2v * __builtin_amdgcn_cvt_pk_f32_fp8(u2.y, false) +
            e3v * __builtin_amdgcn_cvt_pk_f32_fp8(u3.y, false);
    accH += e0v * __builtin_amdgcn_cvt_pk_f32_fp8(u0.y, true) +
            e1v * __builtin_amdgcn_cvt_pk_f32_fp8(u1.y, true);
    accH += e2v * __builtin_amdgcn_cvt_pk_f32_fp8(u2.y, true) +
            e3v * __builtin_amdgcn_cvt_pk_f32_fp8(u3.y, true);
  }
  for (; i < deg; i += G) {
    const unsigned s0 = row[i];
    uint2 u0 = {0, 0};
    if (act) u0 = *(const uint2*)(kv + (size_t)(s0 * (2 * HC)) + coff);
    fx2 t0 = q01 * __builtin_amdgcn_cvt_pk_f32_fp8(u0.x, false) +
             q23 * __builtin_amdgcn_cvt_pk_f32_fp8(u0.x, true);
    float d0 = t0[0] + t0[1];
#pragma unroll
    for (int m = 1; m < RW; m <<= 1) d0 += __shfl_xor(d0, m);
    const float e0 = __expf(d0 * scale_of(C));
    den += e0;
    const fx2 e0v = {e0, e0};
    accL += e0v * __builtin_amdgcn_cvt_pk_f32_fp8(u0.y, false);
    accH += e0v * __builtin_amdgcn_cvt_pk_f32_fp8(u0.y, true);
  }
#pragma unroll
  for (int m = LG; m < 64; m <<= 1) {
    den += __shfl_xor(den, m);
    accL[0] += __shfl_xor(accL[0], m);
    accL[1] += __shfl_xor(accL[1], m);
    accH[0] += __shfl_xor(accH[0], m);
    accH[1] += __shfl_xor(accH[1], m);
  }
  if (lane < ROW) {
    const float inv = 1.f / (den + 1e-16f);
    float4* o = (float4*)(xout + (size_t)n * HC);
    float4 c = o[lane];
    c.x += accL[0] * inv;
    c.y += accL[1] * inv;
    c.z += accH[0] * inv;
    c.w += accH[1] * inv;
    o[lane] = c;
  }
}

// ---------------- K4: parallel segment-sum pool (graph x 16 chunks) -------
__device__ __forceinline__ int lowerb(const int* __restrict__ b, int n,
                                      int key) {
  int lo = 0, hi = n;
  while (lo < hi) {
    int mid = (lo + hi) >> 1;
    if (b[mid] < key) lo = mid + 1;
    else hi = mid;
  }
  return lo;
}

#define SPL 16

__global__ __launch_bounds__(256) void k_pool(const float* __restrict__ x,
                                              const int* __restrict__ batch,
                                              float* __restrict__ gsum) {
  const int b = blockIdx.x >> 4;
  const int s = blockIdx.x & (SPL - 1);
  const int lo = lowerb(batch, NN, b);
  const int hi = lowerb(batch, NN, b + 1);
  const int len = hi - lo;
  const int st = lo + (int)(((long long)len * s) / SPL);
  const int en = lo + (int)(((long long)len * (s + 1)) / SPL);
  const int j = threadIdx.x & 63;
  const int r = threadIdx.x >> 6;
  float acc = 0.f;
  for (int n = st + r; n < en; n += 4) acc += x[(size_t)n * 64 + j];
  __shared__ float red[256];
  red[threadIdx.x] = acc;
  __syncthreads();
  if (threadIdx.x < 64) {
    float v = red[j] + red[64 + j] + red[128 + j] + red[192 + j];
    if (v != 0.f) atomicAdd(&gsum[b * 64 + j], v);
  }
}

// ---------------- K5: final MLP (divide-by-count folded in) ----------------
__global__ void k_mlp(const float* __restrict__ gsum,
                      const int* __restrict__ batch,
                      const float* __restrict__ demo,
                      const float* __restrict__ W1,
                      const float* __restrict__ b1,
                      const float* __restrict__ W2,
                      const float* __restrict__ b2, float* __restrict__ out) {
  const int b = threadIdx.x;
  if (b >= BB) return;
  const int lo = lowerb(batch, NN, b);
  const int hi = lowerb(batch, NN, b + 1);
  const float inv = 1.f / (float)max(hi - lo, 1);
  float f[69];
#pragma unroll
  for (int t = 0; t < 64; ++t) f[t] = gsum[b * 64 + t] * inv;
#pragma unroll
  for (int t = 0; t < 5; ++t) f[64 + t] = demo[b * 5 + t];
  float o0 = b2[0], o1 = b2[1];
  for (int jm = 0; jm < 32; ++jm) {
    float h = b1[jm];
#pragma unroll
    for (int t = 0; t < 69; ++t) h += f[t] * W1[t * 32 + jm];
    h = fmaxf(h, 0.f);
    o0 += h * W2[jm * 2 + 0];
    o1 += h * W2[jm * 2 + 1];
  }
  out[b * 2 + 0] = o0;
  out[b * 2 + 1] = o1;
}

extern "C" void kernel_launch(void* const* d_in, const int* in_sizes, int n_in,
                              void* d_out, int out_size, void* d_ws,
                              size_t ws_size, hipStream_t stream) {
  const int* node_idx = (const int*)d_in[0];
  const int* ei = (const int*)d_in[1];
  const int* batch = (const int*)d_in[2];
  const float* demo = (const float*)d_in[3];
  const float* emb = (const float*)d_in[4];
  const float* P[24];
  for (int i = 0; i < 24; ++i) P[i] = (const float*)d_in[5 + i];
  const float* W1 = (const float*)d_in[29];
  const float* b1 = (const float*)d_in[30];
  const float* W2 = (const float*)d_in[31];
  const float* b2 = (const float*)d_in[32];

  const size_t NS = (size_t)NN * 96;
  float* X0 = (float*)d_ws;
  float* X1 = X0 + NS;
  unsigned short* Q = (unsigned short*)(X0 + 2 * NS);  // NN*96 bf16
  unsigned char* KV = (unsigned char*)(X0 + 3 * NS);   // NN*192 bytes
  int* cursor = (int*)(X0 + 3 * NS + NS / 2);          // NN (== degree)
  unsigned short* ell = (unsigned short*)(cursor + NN);  // NN*MAXDEG u16
  float* GS = (float*)(ell + (size_t)NN * MAXDEG);     // 64*64 partial sums

  hipMemsetAsync(cursor, 0, NN * sizeof(int), stream);

  // fused: ELL scatter (even blocks) || layer-0 qkvs (odd blocks) || GS zero
  {
    const float* const* p = &P[0];
    const int nfb = 2 * ((SBLK + 1 > QBLK0) ? (SBLK + 1) : QBLK0);
    k_fused0<<<nfb, 256, 0, stream>>>(ei, cursor, ell, node_idx, emb, p[0],
                                      p[1], p[2], p[3], p[4], p[5], p[6], p[7],
                                      Q, KV, X1, GS);
  }

  const int nwb = (NN * 64 + 255) / 256;  // one wave per node
  k_agg<3, 32><<<nwb, 256, 0, stream>>>(cursor, ell, Q, KV, X1);

  // layer 1: FIN=96 HC=96 H=1 C=96  (in X1, skip/out X0)
  {
    const float* const* p = &P[8];
    k_qkvs4<96><<<(NN + 63) / 64, 256, 0, stream>>>(
        X1, p[0], p[1], p[2], p[3], p[4], p[5], p[6], p[7], Q, KV, X0);
    k_agg<1, 96><<<nwb, 256, 0, stream>>>(cursor, ell, Q, KV, X0);
  }
  // layer 2: FIN=96 HC=64 H=1 C=64  (in X0, skip/out X1)
  {
    const float* const* p = &P[16];
    k_qkvs4<64><<<(NN + 63) / 64, 256, 0, stream>>>(
        X0, p[0], p[1], p[2], p[3], p[4], p[5], p[6], p[7], Q, KV, X1);
    k_agg<1, 64><<<nwb, 256, 0, stream>>>(cursor, ell, Q, KV, X1);
  }

  k_pool<<<BB * SPL, 256, 0, stream>>>(X1, batch, GS);
  k_mlp<<<1, 64, 0, stream>>>(GS, batch, demo, W1, b1, W2, b2, (float*)d_out);
}